// Round 9
// baseline (496.700 us; speedup 1.0000x reference)
//
#include <hip/hip_runtime.h>
#include <hip/hip_bf16.h>

#define M_DIM 16384
#define N_DIM 4096
#define K_DIM 4096
#define FP8_MAX 448.0f

#define BM 256
#define BN 256
#define NK64 (K_DIM / 64)   // 64 k64-blocks = K-tiles

typedef float f32x16 __attribute__((ext_vector_type(16)));
typedef int i32x4 __attribute__((ext_vector_type(4)));
typedef int i32x8 __attribute__((ext_vector_type(8)));

// Packed fp8 operand layout (A and B identical), matched to the
// mfma_scale_f32_32x32x64_f8f6f4 fragment: lane l holds
//   row = row32*32 + (l&31),  k = k64*64 + (l>>5)*32 + h*16 + j  (h=0,1; j=0..15)
// stored as [row32-block][k64-block][h][lane][16B]  (block = 2048 B).
// GEMM: A staged via global_load_lds (4 x 16 KB buffers); B fragments loaded
// DIRECTLY global->reg (1 KB contiguous per frag; 2 MB/XCD working set ->
// L2-resident). One coarse load block + one unpinned MFMA cluster per step
// (R7's per-MFMA pinning regressed; R6 coarse schedule restored).
// scales = 1.0 e8m0 -> bit-identical to plain fp8 GEMM math.

// ---------------- init ----------------
__global__ void init_amax_kernel(unsigned* amax) {
    if (threadIdx.x < 2) amax[threadIdx.x] = 0u;
}

// ---------------- amax reduction ----------------
__global__ void amax_kernel(const float* __restrict__ p, long n4,
                            unsigned* __restrict__ out) {
    float m = 0.f;
    const float4* p4 = (const float4*)p;
    for (long i = (long)blockIdx.x * blockDim.x + threadIdx.x; i < n4;
         i += (long)gridDim.x * blockDim.x) {
        float4 v = p4[i];
        m = fmaxf(m, fmaxf(fmaxf(fabsf(v.x), fabsf(v.y)),
                           fmaxf(fabsf(v.z), fabsf(v.w))));
    }
#pragma unroll
    for (int off = 32; off > 0; off >>= 1)
        m = fmaxf(m, __shfl_down(m, off));
    __shared__ float smax[4];
    int lane = threadIdx.x & 63, wid = threadIdx.x >> 6;
    if (lane == 0) smax[wid] = m;
    __syncthreads();
    if (threadIdx.x == 0) {
        float bm = fmaxf(fmaxf(smax[0], smax[1]), fmaxf(smax[2], smax[3]));
        atomicMax(out, __float_as_uint(bm));  // positive floats: bit order == value order
    }
}

__device__ __forceinline__ unsigned pack4(float4 v, float s) {
    float a = fminf(fmaxf(v.x * s, -FP8_MAX), FP8_MAX);
    float b = fminf(fmaxf(v.y * s, -FP8_MAX), FP8_MAX);
    float c = fminf(fmaxf(v.z * s, -FP8_MAX), FP8_MAX);
    float d = fminf(fmaxf(v.w * s, -FP8_MAX), FP8_MAX);
    int p = 0;
    p = __builtin_amdgcn_cvt_pk_fp8_f32(a, b, p, false);
    p = __builtin_amdgcn_cvt_pk_fp8_f32(c, d, p, true);
    return (unsigned)p;
}

// ---------------- quantize x (M,K) fp32 -> packed fp8 ----------------
__global__ void quant_x_kernel(const float* __restrict__ x,
                               unsigned char* __restrict__ q,
                               const unsigned* __restrict__ amax) {
    float scale = FP8_MAX / fmaxf(__uint_as_float(amax[0]), 1e-12f);
    int m32 = blockIdx.x;                 // 0..511 (M/32)
    int t = threadIdx.x;
    int lane = t & 63;
    int g = t >> 6;                       // 0..3: k64 sub-block per iteration
    int m = m32 * 32 + (lane & 31);
    int kh = lane >> 5;                   // k-half of the 64-wide K block
    const float* rp = x + (long)m * K_DIM;
    unsigned char* ob = q + (long)m32 * NK64 * 2048;
#pragma unroll
    for (int it = 0; it < 16; ++it) {     // 64 k64-blocks, 4 per iter
        int k64 = it * 4 + g;
        int kb = k64 * 64 + kh * 32;
        float4 v0 = *(const float4*)&rp[kb];
        float4 v1 = *(const float4*)&rp[kb + 4];
        float4 v2 = *(const float4*)&rp[kb + 8];
        float4 v3 = *(const float4*)&rp[kb + 12];
        float4 v4 = *(const float4*)&rp[kb + 16];
        float4 v5 = *(const float4*)&rp[kb + 20];
        float4 v6 = *(const float4*)&rp[kb + 24];
        float4 v7 = *(const float4*)&rp[kb + 28];
        uint4 o0, o1;
        o0.x = pack4(v0, scale); o0.y = pack4(v1, scale);
        o0.z = pack4(v2, scale); o0.w = pack4(v3, scale);
        o1.x = pack4(v4, scale); o1.y = pack4(v5, scale);
        o1.z = pack4(v6, scale); o1.w = pack4(v7, scale);
        *(uint4*)&ob[(long)k64 * 2048 + lane * 16] = o0;          // h=0
        *(uint4*)&ob[(long)k64 * 2048 + 1024 + lane * 16] = o1;   // h=1
    }
}

// ------- quantize + transpose weight (K,N) -> packed fp8 (N-major) -------
__global__ void quant_wt_kernel(const float* __restrict__ w,
                                unsigned char* __restrict__ qw,
                                const unsigned* __restrict__ amax) {
    __shared__ unsigned tile[64][17];     // [k][n-word], pad 17
    float scale = FP8_MAX / fmaxf(__uint_as_float(amax[1]), 1e-12f);
    int b = blockIdx.x;                   // 4096 = (K/64) * (N/64)
    int bk = b & 63, bn = b >> 6;
    int k0 = bk * 64, n0 = bn * 64;
    int t = threadIdx.x;
#pragma unroll
    for (int pass = 0; pass < 4; ++pass) {
        int idx = pass * 256 + t;         // 64 k x 16 words
        int k = idx >> 4, nw = idx & 15;
        float4 v = *(const float4*)&w[(long)(k0 + k) * N_DIM + n0 + nw * 4];
        tile[k][nw] = pack4(v, scale);
    }
    __syncthreads();
    int lane = t & 63, g = t >> 6;
    int n32 = g >> 1, h = g & 1;          // 2 n32-blocks x 2 halves
    int nl = n32 * 32 + (lane & 31);
    int word = nl >> 2, sh = (nl & 3) * 8;
    int kb = (lane >> 5) * 32 + h * 16;
    uint4 o;
    unsigned* ow = (unsigned*)&o;
#pragma unroll
    for (int wd = 0; wd < 4; ++wd) {
        unsigned acc = 0;
#pragma unroll
        for (int j = 0; j < 4; ++j)
            acc |= ((tile[kb + wd * 4 + j][word] >> sh) & 0xffu) << (8 * j);
        ow[wd] = acc;
    }
    long gn32 = (long)(n0 >> 5) + n32;
    *(uint4*)&qw[(gn32 * NK64 + bk) * 2048 + h * 1024 + lane * 16] = o;
}

// ---------------- MX-fp8 GEMM: A via LDS, B direct-to-reg ----------------
__device__ __forceinline__ void stage_qA(const unsigned char* __restrict__ Aseg,
                                         unsigned char* stbuf, int tid, int kt,
                                         int r) {
    int c = r * 512 + tid;                // 0..1023 A chunks
    int f = c >> 7;                       // row32-block 0..7
    int q = c & 127;
    const unsigned char* src = Aseg + ((long)f * NK64 + kt) * 2048 + q * 16;
    __builtin_amdgcn_global_load_lds(
        (const __attribute__((address_space(1))) void*)src,
        (__attribute__((address_space(3))) void*)(stbuf + c * 16), 16, 0, 0);
}

__device__ __forceinline__ i32x8 comb(i32x4 lo, i32x4 hi) {
    return __builtin_shufflevector(lo, hi, 0, 1, 2, 3, 4, 5, 6, 7);
}

// One K-tile step. On entry: frags(kt) in (ca, cb).
// gate(vmcnt/lgkm) -> barrier -> [B(kt+1) glob->reg | SB | dsA(kt+1) +
// stage A(kt+3)] -> SB -> unpinned 8-MFMA cluster on (ca, cb).
// VMEM FIFO per step: B(kt+1) x4 then A-stage(kt+3) x2 -> steady gate vmcnt(2).
template <int VW, bool STG, bool GB, bool NEXT>
__device__ __forceinline__ void tile_step(
    unsigned char* sbase, const unsigned char* __restrict__ Aseg,
    const unsigned char* __restrict__ Bw, int kt, int tid, int lane,
    int wm, i32x4 (&ca)[4][2], i32x4 (&cb)[2][2],
    i32x4 (&na)[4][2], i32x4 (&nb)[2][2], f32x16 (&acc)[4][2]) {
    if constexpr (VW >= 0) {
        if constexpr (VW == 2)
            asm volatile("s_waitcnt vmcnt(2) lgkmcnt(0)" ::: "memory");
        else
            asm volatile("s_waitcnt vmcnt(0) lgkmcnt(0)" ::: "memory");
        __builtin_amdgcn_sched_barrier(0);
        __builtin_amdgcn_s_barrier();
        __builtin_amdgcn_sched_barrier(0);
    }
    if constexpr (GB) {   // B(kt+1) global->reg, FIRST in this step's VMEM FIFO
        const unsigned char* Bn = Bw + (long)(kt + 1) * 2048 + lane * 16;
        nb[0][0] = *(const i32x4*)(Bn);
        nb[0][1] = *(const i32x4*)(Bn + 1024);
        nb[1][0] = *(const i32x4*)(Bn + (long)NK64 * 2048);
        nb[1][1] = *(const i32x4*)(Bn + (long)NK64 * 2048 + 1024);
    }
    __builtin_amdgcn_sched_barrier(0);
    if constexpr (NEXT) {  // A(kt+1) LDS->reg
        const unsigned char* nAl =
            sbase + (size_t)((kt + 1) & 3) * 16384 + wm * 4 * 2048 + lane * 16;
#pragma unroll
        for (int i = 0; i < 4; ++i) {
            na[i][0] = *(const i32x4*)(nAl + i * 2048);
            na[i][1] = *(const i32x4*)(nAl + i * 2048 + 1024);
        }
    }
    if constexpr (STG) {   // stage A(kt+3)
        unsigned char* stbuf = sbase + (size_t)((kt + 3) & 3) * 16384;
        stage_qA(Aseg, stbuf, tid, kt + 3, 0);
        stage_qA(Aseg, stbuf, tid, kt + 3, 1);
    }
    __builtin_amdgcn_sched_barrier(0);
    __builtin_amdgcn_s_setprio(1);
#pragma unroll
    for (int i = 0; i < 4; ++i)
        acc[i][0] = __builtin_amdgcn_mfma_scale_f32_32x32x64_f8f6f4(
            comb(ca[i][0], ca[i][1]), comb(cb[0][0], cb[0][1]), acc[i][0],
            0, 0, 0, 0x7f7f7f7f, 0, 0x7f7f7f7f);
#pragma unroll
    for (int i = 0; i < 4; ++i)
        acc[i][1] = __builtin_amdgcn_mfma_scale_f32_32x32x64_f8f6f4(
            comb(ca[i][0], ca[i][1]), comb(cb[1][0], cb[1][1]), acc[i][1],
            0, 0, 0, 0x7f7f7f7f, 0, 0x7f7f7f7f);
    __builtin_amdgcn_s_setprio(0);
}

__global__ __launch_bounds__(512, 2) void gemm_fp8_kernel(
    const unsigned char* __restrict__ qa, const unsigned char* __restrict__ qw,
    float* __restrict__ out, const unsigned* __restrict__ amax) {
    __shared__ unsigned char lds[4][16384];   // 64 KB: 4 A-buffers

    // XCD swizzle: each XCD owns 2 bn-columns (B working set 2 MB -> L2-fit)
    int b = blockIdx.x;
    int bn = (b & 7) * 2 + ((b >> 3) & 1);    // 0..15
    int bm = b >> 4;                          // 0..63

    int tid = threadIdx.x;
    int lane = tid & 63;
    int w = tid >> 6;
    int wm = w >> 2, wn = w & 3;  // 2x4 wave grid, wave tile 128x64

    f32x16 acc[4][2];
#pragma unroll
    for (int i = 0; i < 4; ++i)
#pragma unroll
        for (int j = 0; j < 2; ++j) acc[i][j] = (f32x16)0.f;

    const unsigned char* Aseg = qa + (long)(bm * 8) * NK64 * 2048;
    const unsigned char* Bw =
        qw + (long)(bn * 8 + wn * 2) * NK64 * 2048;   // wave's 2 n32-panels

    unsigned char* sbase = &lds[0][0];

    i32x4 A0[4][2], B0[2][2], A1[4][2], B1[2][2];

    // prologue: stage A tiles 0,1,2 (6 vmem), load B(0) (4 vmem)
#pragma unroll
    for (int pt = 0; pt < 3; ++pt) {
        stage_qA(Aseg, sbase + (size_t)pt * 16384, tid, pt, 0);
        stage_qA(Aseg, sbase + (size_t)pt * 16384, tid, pt, 1);
    }
#pragma unroll
    for (int j = 0; j < 2; ++j) {
        B0[j][0] = *(const i32x4*)(Bw + (long)j * NK64 * 2048 + lane * 16);
        B0[j][1] = *(const i32x4*)(Bw + (long)j * NK64 * 2048 + 1024 + lane * 16);
    }
    asm volatile("s_waitcnt vmcnt(0)" ::: "memory");   // A(0..2)+B(0) resident
    __builtin_amdgcn_sched_barrier(0);
    __builtin_amdgcn_s_barrier();                      // ..for all waves
    __builtin_amdgcn_sched_barrier(0);
    {   // read tile-0 A fragments
        const unsigned char* Al = sbase + wm * 4 * 2048 + lane * 16;
#pragma unroll
        for (int i = 0; i < 4; ++i) {
            A0[i][0] = *(const i32x4*)(Al + i * 2048);
            A0[i][1] = *(const i32x4*)(Al + i * 2048 + 1024);
        }
    }

    // step 0 (no gate): uses (A0,B0); reads A(1); loads B(1); stages A(3)
    tile_step<-1, true, true, true>(sbase, Aseg, Bw, 0, tid, lane, wm,
                                    A0, B0, A1, B1, acc);
#pragma unroll 1
    for (int kt = 1; kt < 61; kt += 2) {   // covers kt = 1..60
        tile_step<2, true, true, true>(sbase, Aseg, Bw, kt, tid, lane, wm,
                                       A1, B1, A0, B0, acc);
        tile_step<2, true, true, true>(sbase, Aseg, Bw, kt + 1, tid, lane, wm,
                                       A0, B0, A1, B1, acc);
    }
    tile_step<2, false, true, true>(sbase, Aseg, Bw, 61, tid, lane, wm,
                                    A1, B1, A0, B0, acc);
    tile_step<0, false, true, true>(sbase, Aseg, Bw, 62, tid, lane, wm,
                                    A0, B0, A1, B1, acc);
    tile_step<0, false, false, false>(sbase, Aseg, Bw, 63, tid, lane, wm,
                                      A1, B1, A0, B0, acc);

    // epilogue: dequant scale = (amax_x/448) * (amax_w/448)
    float ax = fmaxf(__uint_as_float(amax[0]), 1e-12f);
    float aw = fmaxf(__uint_as_float(amax[1]), 1e-12f);
    float s = ax * aw * (1.0f / (FP8_MAX * FP8_MAX));

    long m0 = (long)bm * BM + wm * 128;
    long n0 = (long)bn * BN + wn * 64;
    int col = lane & 31;
    int rbase = 4 * (lane >> 5);
#pragma unroll
    for (int i = 0; i < 4; ++i)
#pragma unroll
        for (int j = 0; j < 2; ++j)
#pragma unroll
            for (int reg = 0; reg < 16; ++reg) {
                int row = (reg & 3) + 8 * (reg >> 2) + rbase;
                out[(m0 + i * 32 + row) * N_DIM + n0 + j * 32 + col] =
                    acc[i][j][reg] * s;
            }
}

extern "C" void kernel_launch(void* const* d_in, const int* in_sizes, int n_in,
                              void* d_out, int out_size, void* d_ws, size_t ws_size,
                              hipStream_t stream) {
    const float* x = (const float*)d_in[0];       // (8,2048,4096) = (M,K)
    const float* wgt = (const float*)d_in[1];     // (K,N)
    float* out = (float*)d_out;

    // workspace layout
    unsigned* amax = (unsigned*)d_ws;                         // 2 words
    unsigned char* qa = (unsigned char*)d_ws + 256;           // M*K fp8 = 64MB packed
    unsigned char* qw = qa + (long)M_DIM * K_DIM;             // N*K fp8 = 16MB packed

    init_amax_kernel<<<1, 64, 0, stream>>>(amax);
    amax_kernel<<<2048, 256, 0, stream>>>(x, (long)M_DIM * K_DIM / 4, amax + 0);
    amax_kernel<<<1024, 256, 0, stream>>>(wgt, (long)K_DIM * N_DIM / 4, amax + 1);
    quant_x_kernel<<<M_DIM / 32, 256, 0, stream>>>(x, qa, amax);
    quant_wt_kernel<<<(K_DIM / 64) * (N_DIM / 64), 256, 0, stream>>>(wgt, qw, amax);

    dim3 grid((M_DIM / BM) * (N_DIM / BN));  // 1024
    gemm_fp8_kernel<<<grid, 512, 0, stream>>>(qa, qw, out, amax);
}

// Round 12
// 444.536 us; speedup vs baseline: 1.1173x; 1.1173x over previous
//
#include <hip/hip_runtime.h>
#include <hip/hip_bf16.h>

#define M_DIM 16384
#define N_DIM 4096
#define K_DIM 4096
#define FP8_MAX 448.0f

#define BM 256
#define BN 256
#define NK64 (K_DIM / 64)   // 64 k64-blocks = K-tiles

typedef float f32x16 __attribute__((ext_vector_type(16)));
typedef int i32x4 __attribute__((ext_vector_type(4)));
typedef int i32x8 __attribute__((ext_vector_type(8)));

// Packed fp8 operand layout (A and B identical), matched to the
// mfma_scale_f32_32x32x64_f8f6f4 fragment: lane l holds
//   row = row32*32 + (l&31),  k = k64*64 + (l>>5)*32 + h*16 + j  (h=0,1; j=0..15)
// stored as [row32-block][k64-block][h][lane][16B]  (block = 2048 B).
// GEMM = R6-passing kernel VERBATIM (reg-double-buffered, gate-at-top:
//   vmcnt(4)+lgkm0 -> barrier -> reads(kt+1)+stages(kt+3) -> 8-MFMA cluster).
// This round only fuses the pre-passes (5 -> 3 dispatches).
// scales = 1.0 e8m0 -> bit-identical to plain fp8 GEMM math.

// ---------------- init ----------------
__global__ void init_amax_kernel(unsigned* amax) {
    if (threadIdx.x < 2) amax[threadIdx.x] = 0u;
}

// ---------------- fused amax reduction (x then w) ----------------
__global__ void amax2_kernel(const float* __restrict__ x,
                             const float* __restrict__ w,
                             unsigned* __restrict__ amax) {
    const float* p;
    long n4;
    unsigned* out;
    long bid, nb;
    if (blockIdx.x < 2048) {
        p = x; n4 = (long)M_DIM * K_DIM / 4; out = amax + 0;
        bid = blockIdx.x; nb = 2048;
    } else {
        p = w; n4 = (long)K_DIM * N_DIM / 4; out = amax + 1;
        bid = blockIdx.x - 2048; nb = 1024;
    }
    float m = 0.f;
    const float4* p4 = (const float4*)p;
    for (long i = bid * blockDim.x + threadIdx.x; i < n4; i += nb * blockDim.x) {
        float4 v = p4[i];
        m = fmaxf(m, fmaxf(fmaxf(fabsf(v.x), fabsf(v.y)),
                           fmaxf(fabsf(v.z), fabsf(v.w))));
    }
#pragma unroll
    for (int off = 32; off > 0; off >>= 1)
        m = fmaxf(m, __shfl_down(m, off));
    __shared__ float smax[4];
    int lane = threadIdx.x & 63, wid = threadIdx.x >> 6;
    if (lane == 0) smax[wid] = m;
    __syncthreads();
    if (threadIdx.x == 0) {
        float bm = fmaxf(fmaxf(smax[0], smax[1]), fmaxf(smax[2], smax[3]));
        atomicMax(out, __float_as_uint(bm));  // positive floats: bit order == value order
    }
}

__device__ __forceinline__ unsigned pack4(float4 v, float s) {
    float a = fminf(fmaxf(v.x * s, -FP8_MAX), FP8_MAX);
    float b = fminf(fmaxf(v.y * s, -FP8_MAX), FP8_MAX);
    float c = fminf(fmaxf(v.z * s, -FP8_MAX), FP8_MAX);
    float d = fminf(fmaxf(v.w * s, -FP8_MAX), FP8_MAX);
    int p = 0;
    p = __builtin_amdgcn_cvt_pk_fp8_f32(a, b, p, false);
    p = __builtin_amdgcn_cvt_pk_fp8_f32(c, d, p, true);
    return (unsigned)p;
}

// -------- fused quantize: blocks 0..511 -> x ; 512..4607 -> weight --------
__global__ void quant_kernel(const float* __restrict__ x,
                             const float* __restrict__ w,
                             unsigned char* __restrict__ qa,
                             unsigned char* __restrict__ qw,
                             const unsigned* __restrict__ amax) {
    __shared__ unsigned tile[64][17];     // used by the weight path only
    int t = threadIdx.x;
    if (blockIdx.x < 512) {
        // ---- x path: (M,K) fp32 -> packed fp8 ----
        float scale = FP8_MAX / fmaxf(__uint_as_float(amax[0]), 1e-12f);
        int m32 = blockIdx.x;             // 0..511 (M/32)
        int lane = t & 63;
        int g = t >> 6;                   // 0..3: k64 sub-block per iteration
        int m = m32 * 32 + (lane & 31);
        int kh = lane >> 5;               // k-half of the 64-wide K block
        const float* rp = x + (long)m * K_DIM;
        unsigned char* ob = qa + (long)m32 * NK64 * 2048;
#pragma unroll
        for (int it = 0; it < 16; ++it) { // 64 k64-blocks, 4 per iter
            int k64 = it * 4 + g;
            int kb = k64 * 64 + kh * 32;
            float4 v0 = *(const float4*)&rp[kb];
            float4 v1 = *(const float4*)&rp[kb + 4];
            float4 v2 = *(const float4*)&rp[kb + 8];
            float4 v3 = *(const float4*)&rp[kb + 12];
            float4 v4 = *(const float4*)&rp[kb + 16];
            float4 v5 = *(const float4*)&rp[kb + 20];
            float4 v6 = *(const float4*)&rp[kb + 24];
            float4 v7 = *(const float4*)&rp[kb + 28];
            uint4 o0, o1;
            o0.x = pack4(v0, scale); o0.y = pack4(v1, scale);
            o0.z = pack4(v2, scale); o0.w = pack4(v3, scale);
            o1.x = pack4(v4, scale); o1.y = pack4(v5, scale);
            o1.z = pack4(v6, scale); o1.w = pack4(v7, scale);
            *(uint4*)&ob[(long)k64 * 2048 + lane * 16] = o0;          // h=0
            *(uint4*)&ob[(long)k64 * 2048 + 1024 + lane * 16] = o1;   // h=1
        }
    } else {
        // ---- weight path: (K,N) -> packed fp8 (N-major) ----
        float scale = FP8_MAX / fmaxf(__uint_as_float(amax[1]), 1e-12f);
        int b = blockIdx.x - 512;         // 4096 = (K/64) * (N/64)
        int bk = b & 63, bn = b >> 6;
        int k0 = bk * 64, n0 = bn * 64;
#pragma unroll
        for (int pass = 0; pass < 4; ++pass) {
            int idx = pass * 256 + t;     // 64 k x 16 words
            int k = idx >> 4, nw = idx & 15;
            float4 v = *(const float4*)&w[(long)(k0 + k) * N_DIM + n0 + nw * 4];
            tile[k][nw] = pack4(v, scale);
        }
        __syncthreads();
        int lane = t & 63, g = t >> 6;
        int n32 = g >> 1, h = g & 1;      // 2 n32-blocks x 2 halves
        int nl = n32 * 32 + (lane & 31);
        int word = nl >> 2, sh = (nl & 3) * 8;
        int kb = (lane >> 5) * 32 + h * 16;
        uint4 o;
        unsigned* ow = (unsigned*)&o;
#pragma unroll
        for (int wd = 0; wd < 4; ++wd) {
            unsigned acc = 0;
#pragma unroll
            for (int j = 0; j < 4; ++j)
                acc |= ((tile[kb + wd * 4 + j][word] >> sh) & 0xffu) << (8 * j);
            ow[wd] = acc;
        }
        long gn32 = (long)(n0 >> 5) + n32;
        *(uint4*)&qw[(gn32 * NK64 + bk) * 2048 + h * 1024 + lane * 16] = o;
    }
}

// ---------------- MX-fp8 GEMM, reg-double-buffered pipeline ----------------
__device__ __forceinline__ void stage_q(const unsigned char* __restrict__ Aseg,
                                        const unsigned char* __restrict__ Bseg,
                                        unsigned char* stbuf, int tid, int kt, int r) {
    int c = r * 512 + tid;                // 0..2047: 1024 A chunks then 1024 B
    int f = (c >> 7) & 7;                 // row32-block 0..7
    int q = c & 127;
    const unsigned char* src =
        ((c < 1024) ? Aseg : Bseg) + ((long)f * NK64 + kt) * 2048 + q * 16;
    __builtin_amdgcn_global_load_lds(
        (const __attribute__((address_space(1))) void*)src,
        (__attribute__((address_space(3))) void*)(stbuf + c * 16), 16, 0, 0);
}

__device__ __forceinline__ i32x8 comb(i32x4 lo, i32x4 hi) {
    return __builtin_shufflevector(lo, hi, 0, 1, 2, 3, 4, 5, 6, 7);
}

// One K-tile step. On entry: frags for tile kt live in (ca, cb).
// Gate+barrier, then read tile kt+1 frags into (na, nb) and stage tile kt+3,
// then the MFMA cluster on (ca, cb) — loads in flight under the MFMAs.
template <int VW, bool STG, bool NEXT>
__device__ __forceinline__ void tile_step(
    unsigned char* sbase, const unsigned char* __restrict__ Aseg,
    const unsigned char* __restrict__ Bseg, int kt, int tid, int lane,
    int wm, int wn, i32x4 (&ca)[4][2], i32x4 (&cb)[2][2],
    i32x4 (&na)[4][2], i32x4 (&nb)[2][2], f32x16 (&acc)[4][2]) {
    // gate: own staging loads for tile kt+1 landed AND own ds_reads drained;
    // then barrier -> ALL waves' staging for tile kt+1 visible (cross-wave).
    if constexpr (VW == 4)
        asm volatile("s_waitcnt vmcnt(4) lgkmcnt(0)" ::: "memory");
    else if constexpr (VW == 0)
        asm volatile("s_waitcnt vmcnt(0) lgkmcnt(0)" ::: "memory");
    if constexpr (VW >= 0) {
        __builtin_amdgcn_sched_barrier(0);
        __builtin_amdgcn_s_barrier();
        __builtin_amdgcn_sched_barrier(0);
    }

    if constexpr (NEXT) {
        const unsigned char* nbuf = sbase + (size_t)((kt + 1) & 3) * 32768;
        const unsigned char* nAl = nbuf + wm * 4 * 2048;
        const unsigned char* nBl = nbuf + 16384 + wn * 2 * 2048;
#pragma unroll
        for (int i = 0; i < 4; ++i) {
            na[i][0] = *(const i32x4*)(nAl + i * 2048 + lane * 16);
            na[i][1] = *(const i32x4*)(nAl + i * 2048 + 1024 + lane * 16);
        }
#pragma unroll
        for (int j = 0; j < 2; ++j) {
            nb[j][0] = *(const i32x4*)(nBl + j * 2048 + lane * 16);
            nb[j][1] = *(const i32x4*)(nBl + j * 2048 + 1024 + lane * 16);
        }
    }
    if constexpr (STG) {
        unsigned char* stbuf = sbase + (size_t)((kt + 3) & 3) * 32768;
        stage_q(Aseg, Bseg, stbuf, tid, kt + 3, 0);
        stage_q(Aseg, Bseg, stbuf, tid, kt + 3, 1);
        stage_q(Aseg, Bseg, stbuf, tid, kt + 3, 2);
        stage_q(Aseg, Bseg, stbuf, tid, kt + 3, 3);
    }
    // pin: MFMA cluster must not hoist above the read/stage issues
    __builtin_amdgcn_sched_barrier(0);
    __builtin_amdgcn_s_setprio(1);
#pragma unroll
    for (int i = 0; i < 4; ++i)
        acc[i][0] = __builtin_amdgcn_mfma_scale_f32_32x32x64_f8f6f4(
            comb(ca[i][0], ca[i][1]), comb(cb[0][0], cb[0][1]), acc[i][0],
            0, 0, 0, 0x7f7f7f7f, 0, 0x7f7f7f7f);
#pragma unroll
    for (int i = 0; i < 4; ++i)
        acc[i][1] = __builtin_amdgcn_mfma_scale_f32_32x32x64_f8f6f4(
            comb(ca[i][0], ca[i][1]), comb(cb[1][0], cb[1][1]), acc[i][1],
            0, 0, 0, 0x7f7f7f7f, 0, 0x7f7f7f7f);
    __builtin_amdgcn_s_setprio(0);
}

__global__ __launch_bounds__(512, 2) void gemm_fp8_kernel(
    const unsigned char* __restrict__ qa, const unsigned char* __restrict__ qw,
    float* __restrict__ out, const unsigned* __restrict__ amax) {
    __shared__ unsigned char lds[4][32768];   // 128 KB: 4 buffers (A 16K + B 16K)

    // XCD-bijective swizzle (nwg = 1024, divisible by 8)
    int b = blockIdx.x;
    int swz = (b & 7) * 128 + (b >> 3);
    int bm = swz >> 4;            // M/BM = 64 ; N/BN = 16
    int bn = swz & 15;

    int tid = threadIdx.x;
    int lane = tid & 63;
    int w = tid >> 6;
    int wm = w >> 2, wn = w & 3;  // 2x4 wave grid, wave tile 128x64

    f32x16 acc[4][2];
#pragma unroll
    for (int i = 0; i < 4; ++i)
#pragma unroll
        for (int j = 0; j < 2; ++j) acc[i][j] = (f32x16)0.f;

    const unsigned char* Aseg = qa + (long)(bm * 8) * NK64 * 2048;
    const unsigned char* Bseg = qw + (long)(bn * 8) * NK64 * 2048;
    unsigned char* sbase = &lds[0][0];

    i32x4 A0[4][2], B0[2][2], A1[4][2], B1[2][2];

    // prologue: stage tiles 0,1,2 (depth-3)
#pragma unroll
    for (int pt = 0; pt < 3; ++pt)
#pragma unroll
        for (int r = 0; r < 4; ++r)
            stage_q(Aseg, Bseg, sbase + (size_t)pt * 32768, tid, pt, r);
    asm volatile("s_waitcnt vmcnt(0)" ::: "memory");   // all staged tiles resident
    __builtin_amdgcn_sched_barrier(0);
    __builtin_amdgcn_s_barrier();                      // ..for all waves
    __builtin_amdgcn_sched_barrier(0);
    {   // read tile-0 fragments
        const unsigned char* Al = sbase + wm * 4 * 2048 + lane * 16;
        const unsigned char* Bl = sbase + 16384 + wn * 2 * 2048 + lane * 16;
#pragma unroll
        for (int i = 0; i < 4; ++i) {
            A0[i][0] = *(const i32x4*)(Al + i * 2048);
            A0[i][1] = *(const i32x4*)(Al + i * 2048 + 1024);
        }
#pragma unroll
        for (int j = 0; j < 2; ++j) {
            B0[j][0] = *(const i32x4*)(Bl + j * 2048);
            B0[j][1] = *(const i32x4*)(Bl + j * 2048 + 1024);
        }
    }

    // step 0 (no gate): uses (A0,B0); reads tile-1 frags; stages tile 3
    tile_step<-1, true, true>(sbase, Aseg, Bseg, 0, tid, lane, wm, wn,
                              A0, B0, A1, B1, acc);
#pragma unroll 1
    for (int kt = 1; kt < 61; kt += 2) {   // covers kt = 1..60
        tile_step<4, true, true>(sbase, Aseg, Bseg, kt, tid, lane, wm, wn,
                                 A1, B1, A0, B0, acc);
        tile_step<4, true, true>(sbase, Aseg, Bseg, kt + 1, tid, lane, wm, wn,
                                 A0, B0, A1, B1, acc);
    }
    tile_step<4, false, true>(sbase, Aseg, Bseg, 61, tid, lane, wm, wn,
                              A1, B1, A0, B0, acc);
    tile_step<0, false, true>(sbase, Aseg, Bseg, 62, tid, lane, wm, wn,
                              A0, B0, A1, B1, acc);
    tile_step<-1, false, false>(sbase, Aseg, Bseg, 63, tid, lane, wm, wn,
                                A1, B1, A0, B0, acc);

    // epilogue: dequant scale = (amax_x/448) * (amax_w/448)
    float ax = fmaxf(__uint_as_float(amax[0]), 1e-12f);
    float aw = fmaxf(__uint_as_float(amax[1]), 1e-12f);
    float s = ax * aw * (1.0f / (FP8_MAX * FP8_MAX));

    long m0 = (long)bm * BM + wm * 128;
    long n0 = (long)bn * BN + wn * 64;
    int col = lane & 31;
    int rbase = 4 * (lane >> 5);
#pragma unroll
    for (int i = 0; i < 4; ++i)
#pragma unroll
        for (int j = 0; j < 2; ++j)
#pragma unroll
            for (int reg = 0; reg < 16; ++reg) {
                int row = (reg & 3) + 8 * (reg >> 2) + rbase;
                out[(m0 + i * 32 + row) * N_DIM + n0 + j * 32 + col] =
                    acc[i][j][reg] * s;
            }
}

extern "C" void kernel_launch(void* const* d_in, const int* in_sizes, int n_in,
                              void* d_out, int out_size, void* d_ws, size_t ws_size,
                              hipStream_t stream) {
    const float* x = (const float*)d_in[0];       // (8,2048,4096) = (M,K)
    const float* wgt = (const float*)d_in[1];     // (K,N)
    float* out = (float*)d_out;

    // workspace layout
    unsigned* amax = (unsigned*)d_ws;                         // 2 words
    unsigned char* qa = (unsigned char*)d_ws + 256;           // M*K fp8 = 64MB packed
    unsigned char* qw = qa + (long)M_DIM * K_DIM;             // N*K fp8 = 16MB packed

    init_amax_kernel<<<1, 64, 0, stream>>>(amax);
    amax2_kernel<<<3072, 256, 0, stream>>>(x, wgt, amax);
    quant_kernel<<<4608, 256, 0, stream>>>(x, wgt, qa, qw, amax);

    dim3 grid((M_DIM / BM) * (N_DIM / BN));  // 1024
    gemm_fp8_kernel<<<grid, 512, 0, stream>>>(qa, qw, out, amax);
}

// Round 13
// 438.618 us; speedup vs baseline: 1.1324x; 1.0135x over previous
//
#include <hip/hip_runtime.h>
#include <hip/hip_bf16.h>

#define M_DIM 16384
#define N_DIM 4096
#define K_DIM 4096
#define FP8_MAX 448.0f

#define BM 256
#define BN 256
#define NK64 (K_DIM / 64)   // 64 k64-blocks = K-tiles

typedef float f32x16 __attribute__((ext_vector_type(16)));
typedef int i32x4 __attribute__((ext_vector_type(4)));
typedef int i32x8 __attribute__((ext_vector_type(8)));

// Packed fp8 operand layout (A and B identical), matched to the
// mfma_scale_f32_32x32x64_f8f6f4 fragment: lane l holds
//   row = row32*32 + (l&31),  k = k64*64 + (l>>5)*32 + h*16 + j  (h=0,1; j=0..15)
// stored as [row32-block][k64-block][h][lane][16B]  (block = 2048 B).
// GEMM = R12 skeleton (passing) + sync-neutral 2-phase pacing:
//   gate(vmcnt4+lgkm0) -> bar -> {reads A0,A1,B0 (kt+1); stages r0,r1 (kt+3);
//   MFMA col0} -> mid bar -> {reads A2,A3,B1; stages r2,r3; MFMA col1}.
// vmem FIFO order r0..r3 unchanged vs R12 -> identical gate accounting.
// Prologue drains vmcnt(0) (all 3 prefetched tiles resident) before reads.
// scales = 1.0 e8m0 -> bit-identical to plain fp8 GEMM math.

// ---------------- init ----------------
__global__ void init_amax_kernel(unsigned* amax) {
    if (threadIdx.x < 2) amax[threadIdx.x] = 0u;
}

// ---------------- fused amax reduction (x then w) ----------------
__global__ void amax2_kernel(const float* __restrict__ x,
                             const float* __restrict__ w,
                             unsigned* __restrict__ amax) {
    const float* p;
    long n4;
    unsigned* out;
    long bid, nb;
    if (blockIdx.x < 2048) {
        p = x; n4 = (long)M_DIM * K_DIM / 4; out = amax + 0;
        bid = blockIdx.x; nb = 2048;
    } else {
        p = w; n4 = (long)K_DIM * N_DIM / 4; out = amax + 1;
        bid = blockIdx.x - 2048; nb = 1024;
    }
    float m = 0.f;
    const float4* p4 = (const float4*)p;
    for (long i = bid * blockDim.x + threadIdx.x; i < n4; i += nb * blockDim.x) {
        float4 v = p4[i];
        m = fmaxf(m, fmaxf(fmaxf(fabsf(v.x), fabsf(v.y)),
                           fmaxf(fabsf(v.z), fabsf(v.w))));
    }
#pragma unroll
    for (int off = 32; off > 0; off >>= 1)
        m = fmaxf(m, __shfl_down(m, off));
    __shared__ float smax[4];
    int lane = threadIdx.x & 63, wid = threadIdx.x >> 6;
    if (lane == 0) smax[wid] = m;
    __syncthreads();
    if (threadIdx.x == 0) {
        float bm = fmaxf(fmaxf(smax[0], smax[1]), fmaxf(smax[2], smax[3]));
        atomicMax(out, __float_as_uint(bm));  // positive floats: bit order == value order
    }
}

__device__ __forceinline__ unsigned pack4(float4 v, float s) {
    float a = fminf(fmaxf(v.x * s, -FP8_MAX), FP8_MAX);
    float b = fminf(fmaxf(v.y * s, -FP8_MAX), FP8_MAX);
    float c = fminf(fmaxf(v.z * s, -FP8_MAX), FP8_MAX);
    float d = fminf(fmaxf(v.w * s, -FP8_MAX), FP8_MAX);
    int p = 0;
    p = __builtin_amdgcn_cvt_pk_fp8_f32(a, b, p, false);
    p = __builtin_amdgcn_cvt_pk_fp8_f32(c, d, p, true);
    return (unsigned)p;
}

// -------- fused quantize: blocks 0..511 -> x ; 512..4607 -> weight --------
__global__ void quant_kernel(const float* __restrict__ x,
                             const float* __restrict__ w,
                             unsigned char* __restrict__ qa,
                             unsigned char* __restrict__ qw,
                             const unsigned* __restrict__ amax) {
    __shared__ unsigned tile[64][17];     // used by the weight path only
    int t = threadIdx.x;
    if (blockIdx.x < 512) {
        // ---- x path: (M,K) fp32 -> packed fp8 ----
        float scale = FP8_MAX / fmaxf(__uint_as_float(amax[0]), 1e-12f);
        int m32 = blockIdx.x;             // 0..511 (M/32)
        int lane = t & 63;
        int g = t >> 6;                   // 0..3: k64 sub-block per iteration
        int m = m32 * 32 + (lane & 31);
        int kh = lane >> 5;               // k-half of the 64-wide K block
        const float* rp = x + (long)m * K_DIM;
        unsigned char* ob = qa + (long)m32 * NK64 * 2048;
#pragma unroll
        for (int it = 0; it < 16; ++it) { // 64 k64-blocks, 4 per iter
            int k64 = it * 4 + g;
            int kb = k64 * 64 + kh * 32;
            float4 v0 = *(const float4*)&rp[kb];
            float4 v1 = *(const float4*)&rp[kb + 4];
            float4 v2 = *(const float4*)&rp[kb + 8];
            float4 v3 = *(const float4*)&rp[kb + 12];
            float4 v4 = *(const float4*)&rp[kb + 16];
            float4 v5 = *(const float4*)&rp[kb + 20];
            float4 v6 = *(const float4*)&rp[kb + 24];
            float4 v7 = *(const float4*)&rp[kb + 28];
            uint4 o0, o1;
            o0.x = pack4(v0, scale); o0.y = pack4(v1, scale);
            o0.z = pack4(v2, scale); o0.w = pack4(v3, scale);
            o1.x = pack4(v4, scale); o1.y = pack4(v5, scale);
            o1.z = pack4(v6, scale); o1.w = pack4(v7, scale);
            *(uint4*)&ob[(long)k64 * 2048 + lane * 16] = o0;          // h=0
            *(uint4*)&ob[(long)k64 * 2048 + 1024 + lane * 16] = o1;   // h=1
        }
    } else {
        // ---- weight path: (K,N) -> packed fp8 (N-major) ----
        float scale = FP8_MAX / fmaxf(__uint_as_float(amax[1]), 1e-12f);
        int b = blockIdx.x - 512;         // 4096 = (K/64) * (N/64)
        int bk = b & 63, bn = b >> 6;
        int k0 = bk * 64, n0 = bn * 64;
#pragma unroll
        for (int pass = 0; pass < 4; ++pass) {
            int idx = pass * 256 + t;     // 64 k x 16 words
            int k = idx >> 4, nw = idx & 15;
            float4 v = *(const float4*)&w[(long)(k0 + k) * N_DIM + n0 + nw * 4];
            tile[k][nw] = pack4(v, scale);
        }
        __syncthreads();
        int lane = t & 63, g = t >> 6;
        int n32 = g >> 1, h = g & 1;      // 2 n32-blocks x 2 halves
        int nl = n32 * 32 + (lane & 31);
        int word = nl >> 2, sh = (nl & 3) * 8;
        int kb = (lane >> 5) * 32 + h * 16;
        uint4 o;
        unsigned* ow = (unsigned*)&o;
#pragma unroll
        for (int wd = 0; wd < 4; ++wd) {
            unsigned acc = 0;
#pragma unroll
            for (int j = 0; j < 4; ++j)
                acc |= ((tile[kb + wd * 4 + j][word] >> sh) & 0xffu) << (8 * j);
            ow[wd] = acc;
        }
        long gn32 = (long)(n0 >> 5) + n32;
        *(uint4*)&qw[(gn32 * NK64 + bk) * 2048 + h * 1024 + lane * 16] = o;
    }
}

// ---------------- MX-fp8 GEMM, 2-phase paced, reg-double-buffered ----------------
__device__ __forceinline__ void stage_q(const unsigned char* __restrict__ Aseg,
                                        const unsigned char* __restrict__ Bseg,
                                        unsigned char* stbuf, int tid, int kt, int r) {
    int c = r * 512 + tid;                // 0..2047: 1024 A chunks then 1024 B
    int f = (c >> 7) & 7;                 // row32-block 0..7
    int q = c & 127;
    const unsigned char* src =
        ((c < 1024) ? Aseg : Bseg) + ((long)f * NK64 + kt) * 2048 + q * 16;
    __builtin_amdgcn_global_load_lds(
        (const __attribute__((address_space(1))) void*)src,
        (__attribute__((address_space(3))) void*)(stbuf + c * 16), 16, 0, 0);
}

__device__ __forceinline__ i32x8 comb(i32x4 lo, i32x4 hi) {
    return __builtin_shufflevector(lo, hi, 0, 1, 2, 3, 4, 5, 6, 7);
}

#define SB() __builtin_amdgcn_sched_barrier(0)

// One K-tile step. On entry: frags for tile kt live in (ca, cb).
// Same gates/vmem-order as the passing R12 kernel; only difference:
// reads/stages split into two halves with a uniform mid s_barrier,
// each half followed by a 4-MFMA cluster (sync-neutral reorder).
template <int VW, bool STG, bool NEXT>
__device__ __forceinline__ void tile_step(
    unsigned char* sbase, const unsigned char* __restrict__ Aseg,
    const unsigned char* __restrict__ Bseg, int kt, int tid, int lane,
    int wm, int wn, i32x4 (&ca)[4][2], i32x4 (&cb)[2][2],
    i32x4 (&na)[4][2], i32x4 (&nb)[2][2], f32x16 (&acc)[4][2]) {
    // gate: own staging loads for tile kt+1 landed AND own ds_reads drained;
    // then barrier -> ALL waves' staging for tile kt+1 visible (cross-wave).
    if constexpr (VW == 4)
        asm volatile("s_waitcnt vmcnt(4) lgkmcnt(0)" ::: "memory");
    else if constexpr (VW == 0)
        asm volatile("s_waitcnt vmcnt(0) lgkmcnt(0)" ::: "memory");
    if constexpr (VW >= 0) {
        SB();
        __builtin_amdgcn_s_barrier();
        SB();
    }

    const unsigned char* nbuf = sbase + (size_t)((kt + 1) & 3) * 32768;
    const unsigned char* nAl = nbuf + wm * 4 * 2048 + lane * 16;
    const unsigned char* nBl = nbuf + 16384 + wn * 2 * 2048 + lane * 16;
    unsigned char* stbuf = sbase + (size_t)((kt + 3) & 3) * 32768;

    // ---- phase 0: reads A0,A1,B0 of kt+1 ; stages r0,r1 ; MFMA col 0 ----
    if constexpr (NEXT) {
        na[0][0] = *(const i32x4*)(nAl + 0 * 2048);
        na[0][1] = *(const i32x4*)(nAl + 0 * 2048 + 1024);
        na[1][0] = *(const i32x4*)(nAl + 1 * 2048);
        na[1][1] = *(const i32x4*)(nAl + 1 * 2048 + 1024);
        nb[0][0] = *(const i32x4*)(nBl);
        nb[0][1] = *(const i32x4*)(nBl + 1024);
    }
    if constexpr (STG) {
        stage_q(Aseg, Bseg, stbuf, tid, kt + 3, 0);
        stage_q(Aseg, Bseg, stbuf, tid, kt + 3, 1);
    }
    SB();
    __builtin_amdgcn_s_setprio(1);
#pragma unroll
    for (int i = 0; i < 4; ++i)
        acc[i][0] = __builtin_amdgcn_mfma_scale_f32_32x32x64_f8f6f4(
            comb(ca[i][0], ca[i][1]), comb(cb[0][0], cb[0][1]), acc[i][0],
            0, 0, 0, 0x7f7f7f7f, 0, 0x7f7f7f7f);
    __builtin_amdgcn_s_setprio(0);
    SB();
    __builtin_amdgcn_s_barrier();     // mid pacing barrier (uniform, data-free)
    SB();

    // ---- phase 1: reads A2,A3,B1 of kt+1 ; stages r2,r3 ; MFMA col 1 ----
    if constexpr (NEXT) {
        na[2][0] = *(const i32x4*)(nAl + 2 * 2048);
        na[2][1] = *(const i32x4*)(nAl + 2 * 2048 + 1024);
        na[3][0] = *(const i32x4*)(nAl + 3 * 2048);
        na[3][1] = *(const i32x4*)(nAl + 3 * 2048 + 1024);
        nb[1][0] = *(const i32x4*)(nBl + 2048);
        nb[1][1] = *(const i32x4*)(nBl + 2048 + 1024);
    }
    if constexpr (STG) {
        stage_q(Aseg, Bseg, stbuf, tid, kt + 3, 2);
        stage_q(Aseg, Bseg, stbuf, tid, kt + 3, 3);
    }
    SB();
    __builtin_amdgcn_s_setprio(1);
#pragma unroll
    for (int i = 0; i < 4; ++i)
        acc[i][1] = __builtin_amdgcn_mfma_scale_f32_32x32x64_f8f6f4(
            comb(ca[i][0], ca[i][1]), comb(cb[1][0], cb[1][1]), acc[i][1],
            0, 0, 0, 0x7f7f7f7f, 0, 0x7f7f7f7f);
    __builtin_amdgcn_s_setprio(0);
}

__global__ __launch_bounds__(512, 2) void gemm_fp8_kernel(
    const unsigned char* __restrict__ qa, const unsigned char* __restrict__ qw,
    float* __restrict__ out, const unsigned* __restrict__ amax) {
    __shared__ unsigned char lds[4][32768];   // 128 KB: 4 buffers (A 16K + B 16K)

    // XCD-bijective swizzle (nwg = 1024, divisible by 8)
    int b = blockIdx.x;
    int swz = (b & 7) * 128 + (b >> 3);
    int bm = swz >> 4;            // M/BM = 64 ; N/BN = 16
    int bn = swz & 15;

    int tid = threadIdx.x;
    int lane = tid & 63;
    int w = tid >> 6;
    int wm = w >> 2, wn = w & 3;  // 2x4 wave grid, wave tile 128x64

    f32x16 acc[4][2];
#pragma unroll
    for (int i = 0; i < 4; ++i)
#pragma unroll
        for (int j = 0; j < 2; ++j) acc[i][j] = (f32x16)0.f;

    const unsigned char* Aseg = qa + (long)(bm * 8) * NK64 * 2048;
    const unsigned char* Bseg = qw + (long)(bn * 8) * NK64 * 2048;
    unsigned char* sbase = &lds[0][0];

    i32x4 A0[4][2], B0[2][2], A1[4][2], B1[2][2];

    // prologue: stage tiles 0,1,2 (depth-3)
#pragma unroll
    for (int pt = 0; pt < 3; ++pt)
#pragma unroll
        for (int r = 0; r < 4; ++r)
            stage_q(Aseg, Bseg, sbase + (size_t)pt * 32768, tid, pt, r);
    asm volatile("s_waitcnt vmcnt(0)" ::: "memory");   // all staged tiles resident
    SB();
    __builtin_amdgcn_s_barrier();                      // ..for all waves
    SB();
    {   // read tile-0 fragments
        const unsigned char* Al = sbase + wm * 4 * 2048 + lane * 16;
        const unsigned char* Bl = sbase + 16384 + wn * 2 * 2048 + lane * 16;
#pragma unroll
        for (int i = 0; i < 4; ++i) {
            A0[i][0] = *(const i32x4*)(Al + i * 2048);
            A0[i][1] = *(const i32x4*)(Al + i * 2048 + 1024);
        }
#pragma unroll
        for (int j = 0; j < 2; ++j) {
            B0[j][0] = *(const i32x4*)(Bl + j * 2048);
            B0[j][1] = *(const i32x4*)(Bl + j * 2048 + 1024);
        }
    }

    // step 0 (no gate): uses (A0,B0); reads tile-1 frags; stages tile 3
    tile_step<-1, true, true>(sbase, Aseg, Bseg, 0, tid, lane, wm, wn,
                              A0, B0, A1, B1, acc);
#pragma unroll 1
    for (int kt = 1; kt < 61; kt += 2) {   // covers kt = 1..60
        tile_step<4, true, true>(sbase, Aseg, Bseg, kt, tid, lane, wm, wn,
                                 A1, B1, A0, B0, acc);
        tile_step<4, true, true>(sbase, Aseg, Bseg, kt + 1, tid, lane, wm, wn,
                                 A0, B0, A1, B1, acc);
    }
    tile_step<4, false, true>(sbase, Aseg, Bseg, 61, tid, lane, wm, wn,
                              A1, B1, A0, B0, acc);
    tile_step<0, false, true>(sbase, Aseg, Bseg, 62, tid, lane, wm, wn,
                              A0, B0, A1, B1, acc);
    tile_step<-1, false, false>(sbase, Aseg, Bseg, 63, tid, lane, wm, wn,
                                A1, B1, A0, B0, acc);

    // epilogue: dequant scale = (amax_x/448) * (amax_w/448)
    float ax = fmaxf(__uint_as_float(amax[0]), 1e-12f);
    float aw = fmaxf(__uint_as_float(amax[1]), 1e-12f);
    float s = ax * aw * (1.0f / (FP8_MAX * FP8_MAX));

    long m0 = (long)bm * BM + wm * 128;
    long n0 = (long)bn * BN + wn * 64;
    int col = lane & 31;
    int rbase = 4 * (lane >> 5);
#pragma unroll
    for (int i = 0; i < 4; ++i)
#pragma unroll
        for (int j = 0; j < 2; ++j)
#pragma unroll
            for (int reg = 0; reg < 16; ++reg) {
                int row = (reg & 3) + 8 * (reg >> 2) + rbase;
                out[(m0 + i * 32 + row) * N_DIM + n0 + j * 32 + col] =
                    acc[i][j][reg] * s;
            }
}

extern "C" void kernel_launch(void* const* d_in, const int* in_sizes, int n_in,
                              void* d_out, int out_size, void* d_ws, size_t ws_size,
                              hipStream_t stream) {
    const float* x = (const float*)d_in[0];       // (8,2048,4096) = (M,K)
    const float* wgt = (const float*)d_in[1];     // (K,N)
    float* out = (float*)d_out;

    // workspace layout
    unsigned* amax = (unsigned*)d_ws;                         // 2 words
    unsigned char* qa = (unsigned char*)d_ws + 256;           // M*K fp8 = 64MB packed
    unsigned char* qw = qa + (long)M_DIM * K_DIM;             // N*K fp8 = 16MB packed

    init_amax_kernel<<<1, 64, 0, stream>>>(amax);
    amax2_kernel<<<3072, 256, 0, stream>>>(x, wgt, amax);
    quant_kernel<<<4608, 256, 0, stream>>>(x, wgt, qa, qw, amax);

    dim3 grid((M_DIM / BM) * (N_DIM / BN));  // 1024
    gemm_fp8_kernel<<<grid, 512, 0, stream>>>(qa, qw, out, amax);
}